// Round 10
// baseline (50.416 us; speedup 1.0000x reference)
//
#include <hip/hip_runtime.h>
#include <math.h>

#define NCLS   20
#define MCELLS 49
#define FEAT   30
#define ITEMF  1470   // MCELLS * FEAT
#define IPW    4      // items per wave (2-deep software pipeline)

typedef unsigned long long u64;
typedef unsigned int u32;
typedef float f32x4 __attribute__((ext_vector_type(4)));

__device__ __forceinline__ void nts(float* p, float v) { __builtin_nontemporal_store(v, p); }
__device__ __forceinline__ float bperm(int srcLane, float v) {
  return __int_as_float(__builtin_amdgcn_ds_bpermute(srcLane << 2, __float_as_int(v)));
}

struct Item { float2 v[15]; };

__device__ __forceinline__ void loadItem(Item& it, const float* __restrict__ x,
                                         long n, int N, bool cellv, int m) {
  if ((n < N) && cellv) {
    const float2* Lp = (const float2*)(x + (size_t)n * ITEMF + m * FEAT);
#pragma unroll
    for (int j = 0; j < 15; ++j) it.v[j] = Lp[j];
  }
}

__device__ __forceinline__ void processItem(const Item& it, long n, int N, int lane,
                                            const float* __restrict__ x,
                                            float* out0, float* out1, float* out2,
                                            float* out3, float* out4, float* out5,
                                            float* out6) {
  if (n >= N) return;                 // wave-uniform (n uniform across the wave)
  const int m = lane;
  const bool cellv = (m < MCELLS);
  const float* item = x + (size_t)n * ITEMF;

  // ---- class logits copy: global->global gather (L1/L2/L3-served), NT stores ----
  {
    float* dst = out0 + (size_t)n * (MCELLS * NCLS);
#pragma unroll
    for (int i = 0; i < 16; ++i) {
      int idx = lane + i * 64;
      if (idx < MCELLS * NCLS) {
        int c = idx / NCLS;
        int k = idx - c * NCLS;
        nts(dst + idx, item[c * FEAT + k]);
      }
    }
  }

  // ---- per-cell compute from the prefetched registers ----
  int   labi = 0;
  float conf = 0.f;
  float x0 = 0.f, y0 = 0.f, x1 = 0.f, y1 = 0.f;
  bool  reserve = false;

  if (cellv) {
    // label = argmax over 20 logits (first-max), == argmax(softmax)
    float bestv = it.v[0].x;
    if (it.v[0].y > bestv) { bestv = it.v[0].y; labi = 1; }
#pragma unroll
    for (int j = 1; j < 10; ++j) {
      if (it.v[j].x > bestv) { bestv = it.v[j].x; labi = 2 * j; }
      if (it.v[j].y > bestv) { bestv = it.v[j].y; labi = 2 * j + 1; }
    }

    // bbox block elems 20..29: v[10].x=bx0 .y=by0 v[11].x=bw0 .y=bh0 v[12].x=c0
    //                          v[12].y=bx1 v[13].x=by1 .y=bw1 v[14].x=bh1 .y=c1
    float c0 = it.v[12].x, c1 = it.v[14].y;
    bool sel1 = (c1 > c0);             // argmax first-max tie rule
    float bx = sel1 ? it.v[12].y : it.v[10].x;
    float by = sel1 ? it.v[13].x : it.v[10].y;
    float bw = sel1 ? it.v[13].y : it.v[11].x;
    float bh = sel1 ? it.v[14].x : it.v[11].y;
    conf = sel1 ? c1 : c0;

    float xg = (float)(m % 7), yg = (float)(m / 7);
    float cx = (bx + xg) / 7.0f, cy = (by + yg) / 7.0f;
    float hw = bw * 0.5f, hh = bh * 0.5f;
    x0 = fminf(fmaxf((cx - hw) * 448.0f, 0.f), 448.f);
    y0 = fminf(fmaxf((cy - hh) * 448.0f, 0.f), 448.f);
    x1 = fminf(fmaxf((cx + hw) * 448.0f, 0.f), 448.f);
    y1 = fminf(fmaxf((cy + hh) * 448.0f, 0.f), 448.f);
    reserve = (conf > 0.1f);

    size_t ci = (size_t)n * MCELLS + m;
    float* yb = out1 + ci * 5;
    nts(yb + 0, bx); nts(yb + 1, by); nts(yb + 2, bw); nts(yb + 3, bh); nts(yb + 4, conf);
    f32x4 bx4 = { x0, y0, x1, y1 };
    __builtin_nontemporal_store(bx4, (f32x4*)(out2 + ci * 4));
    nts(out3 + ci, conf);
    nts(out4 + ci, (float)labi);
    nts(out6 + ci, reserve ? 1.0f : 0.0f);
  }

  // ================= NMS: sort-free, scan-free =================
  // Cross-label IoU is exactly 0 under the reference's class-offset scheme, so
  // the greedy scan == per-class greedy; keep(i) is the unique fixed point of
  // keep(i) <=> no kept candidate-suppressor (same label, higher priority, IoU>0.7).
  const bool meValid = (cellv && reserve);
  const u64 validb = __ballot(meValid);

  // same-label mask via 5 bit-ballots over the label bits (labi < 32)
  u64 same = ~0ull;
#pragma unroll
  for (int b = 0; b < 5; ++b) {
    u64 bb = __ballot(((labi >> b) & 1) != 0);
    same &= ((labi >> b) & 1) ? bb : ~bb;
  }
  u64 peers = same & validb & ~(1ull << lane);
  if (!meValid) peers = 0;

  // wave-uniform trip count = max peer count over the wave
  int pc = __popcll(peers);
#pragma unroll
  for (int d = 1; d < 64; d <<= 1) {
    int o = __shfl_xor(pc, d);
    pc = pc > o ? pc : o;
  }
  const int T = __builtin_amdgcn_readfirstlane(pc);

  // candidate-suppressor mask in ORIGINAL index space; iterations pipeline
  const float area_i = fmaxf(x1 - x0, 0.f) * fmaxf(y1 - y0, 0.f);
  u64 candme = 0;
  u64 rem = peers;
  for (int t = 0; t < T; ++t) {
    int j = rem ? (int)__builtin_ctzll(rem) : lane;   // dummy self-compare when exhausted
    rem &= rem - 1;
    float cj  = bperm(j, conf);
    float jx0 = bperm(j, x0), jy0 = bperm(j, y0);
    float jx1 = bperm(j, x1), jy1 = bperm(j, y1);
    bool prec = (cj > conf) || ((cj == conf) && (j < lane));  // stable-sort priority
    float aj = fmaxf(jx1 - jx0, 0.f) * fmaxf(jy1 - jy0, 0.f);
    float iw = fminf(jx1, x1) - fmaxf(jx0, x0);
    float ih = fminf(jy1, y1) - fmaxf(jy0, y0);
    float inter = fmaxf(iw, 0.f) * fmaxf(ih, 0.f);
    float uni = aj + area_i - inter;
    bool sup = prec && (inter > 0.7f * fmaxf(uni, 1e-9f));
    candme |= sup ? (1ull << j) : 0ull;
  }

  // ballot fixed-point: per class, the highest-priority undecided box is always
  // ready -> guaranteed progress; rounds <= max suppression-chain depth (~2-3).
  u64 undecided = validb, kept = 0;
  while (undecided) {
    bool meUnd  = meValid && ((undecided >> lane) & 1ull);
    bool ready  = meUnd && ((candme & undecided) == 0ull);
    u64 readyb  = __ballot(ready);
    u64 keptb   = __ballot(ready && ((candme & kept) == 0ull));
    kept |= keptb;
    undecided &= ~readyb;
  }

  if (cellv) nts(out5 + (size_t)n * MCELLS + m, (float)((kept >> lane) & 1ull));
}

__global__ __launch_bounds__(256) void yolo_post(const float* __restrict__ x,
                                                 float* __restrict__ out,
                                                 int N) {
  const int wave = threadIdx.x >> 6;
  const int lane = threadIdx.x & 63;
  const int gw = blockIdx.x * 4 + wave;
  const long i0 = (long)gw * IPW;
  if (i0 >= N) return;   // wave-uniform exit; no LDS, no barriers

  const int m = lane;
  const bool cellv = (m < MCELLS);

  // ---- output section pointers (flat concat in return order) ----
  const size_t NM = (size_t)N * MCELLS;
  float* out0 = out;              // class_logits  N*M*20
  float* out1 = out0 + NM * 20;   // yolo_bboxes   N*M*5
  float* out2 = out1 + NM * 5;    // boxes         N*M*4
  float* out3 = out2 + NM * 4;    // scores        N*M
  float* out4 = out3 + NM;        // labels        N*M
  float* out5 = out4 + NM;        // keep_mask     N*M
  float* out6 = out5 + NM;        // reserve_mask  N*M

  // 2-deep software pipeline over IPW consecutive items:
  // next item's AoS loads are in flight while current item computes its
  // stores + NMS (the no-VMEM phase) -> memory pipe stays busy.
  Item A, B;
  loadItem(A, x, i0 + 0, N, cellv, m);
  loadItem(B, x, i0 + 1, N, cellv, m);
  processItem(A, i0 + 0, N, lane, x, out0, out1, out2, out3, out4, out5, out6);
  loadItem(A, x, i0 + 2, N, cellv, m);
  processItem(B, i0 + 1, N, lane, x, out0, out1, out2, out3, out4, out5, out6);
  loadItem(B, x, i0 + 3, N, cellv, m);
  processItem(A, i0 + 2, N, lane, x, out0, out1, out2, out3, out4, out5, out6);
  processItem(B, i0 + 3, N, lane, x, out0, out1, out2, out3, out4, out5, out6);
}

extern "C" void kernel_launch(void* const* d_in, const int* in_sizes, int n_in,
                              void* d_out, int out_size, void* d_ws, size_t ws_size,
                              hipStream_t stream) {
  const float* x = (const float*)d_in[0];
  float* out = (float*)d_out;
  int N = in_sizes[0] / ITEMF;
  int waves = (N + IPW - 1) / IPW;        // one wave per IPW items
  int grid = (waves + 3) / 4;             // 4 waves per 256-thread block
  yolo_post<<<grid, 256, 0, stream>>>(x, out, N);
}

// Round 12
// 48.904 us; speedup vs baseline: 1.0309x; 1.0309x over previous
//
#include <hip/hip_runtime.h>
#include <math.h>

#define NCLS   20
#define MCELLS 49
#define FEAT   30
#define ITEMF  1470   // MCELLS * FEAT

typedef unsigned long long u64;
typedef unsigned int u32;
typedef float f32x4 __attribute__((ext_vector_type(4)));

__device__ __forceinline__ void nts(float* p, float v) { __builtin_nontemporal_store(v, p); }
__device__ __forceinline__ float bperm(int srcLane, float v) {
  return __int_as_float(__builtin_amdgcn_ds_bpermute(srcLane << 2, __float_as_int(v)));
}

// ================= K1: streaming kernel (everything except keep_mask) ==========
// Homogeneous per wave: AoS loads -> short VALU -> store burst. No NMS bubble;
// input read exactly once (logits go through a per-wave LDS transpose).
__global__ __launch_bounds__(256) void yolo_stream(const float* __restrict__ x,
                                                   float* __restrict__ out,
                                                   int N) {
  const int wave = threadIdx.x >> 6;
  const int lane = threadIdx.x & 63;
  const int n = blockIdx.x * 4 + wave;

  __shared__ float slog[4][MCELLS * NCLS];   // 3920 B per wave, 15.7 KB/block

  if (n >= N) return;   // wave-uniform exit; no block-wide barriers used

  const size_t NM = (size_t)N * MCELLS;
  float* out0 = out;              // class_logits  N*M*20
  float* out1 = out0 + NM * 20;   // yolo_bboxes   N*M*5
  float* out2 = out1 + NM * 5;    // boxes         N*M*4
  float* out3 = out2 + NM * 4;    // scores        N*M
  float* out4 = out3 + NM;        // labels        N*M
  float* out6 = out4 + NM * 2;    // reserve_mask  N*M  (skip out5=keep, written by K2)

  const int m = lane;
  const bool cellv = (m < MCELLS);

  // ---- per-lane AoS loads: lane m owns cell m's 30 floats ----
  float2 v[15];
  if (cellv) {
    const float2* Lp = (const float2*)(x + (size_t)n * ITEMF + m * FEAT);
#pragma unroll
    for (int j = 0; j < 15; ++j) v[j] = Lp[j];
  } else {
#pragma unroll
    for (int j = 0; j < 15; ++j) v[j] = make_float2(0.f, 0.f);
  }

  // ---- logits: registers -> LDS transpose -> coalesced NT stores ----
  if (cellv) {
    float2* dst = (float2*)&slog[wave][m * NCLS];
#pragma unroll
    for (int j = 0; j < 10; ++j) dst[j] = v[j];
  }
  __threadfence_block();   // wave-synchronous: LDS writes before cross-lane reads
  {
    float* dst = out0 + (size_t)n * (MCELLS * NCLS);
    const float* s = slog[wave];
#pragma unroll
    for (int i = 0; i < 16; ++i) {
      int idx = lane + i * 64;
      if (idx < MCELLS * NCLS) nts(dst + idx, s[idx]);
    }
  }

  // ---- per-cell compute + stores ----
  if (cellv) {
    int labi = 0;
    float bestv = v[0].x;
    if (v[0].y > bestv) { bestv = v[0].y; labi = 1; }
#pragma unroll
    for (int j = 1; j < 10; ++j) {
      if (v[j].x > bestv) { bestv = v[j].x; labi = 2 * j; }
      if (v[j].y > bestv) { bestv = v[j].y; labi = 2 * j + 1; }
    }

    // bbox block elems 20..29: v[10].x=bx0 .y=by0 v[11].x=bw0 .y=bh0 v[12].x=c0
    //                          v[12].y=bx1 v[13].x=by1 .y=bw1 v[14].x=bh1 .y=c1
    float c0 = v[12].x, c1 = v[14].y;
    bool sel1 = (c1 > c0);             // argmax first-max tie rule
    float bx = sel1 ? v[12].y : v[10].x;
    float by = sel1 ? v[13].x : v[10].y;
    float bw = sel1 ? v[13].y : v[11].x;
    float bh = sel1 ? v[14].x : v[11].y;
    float conf = sel1 ? c1 : c0;

    float xg = (float)(m % 7), yg = (float)(m / 7);
    float cx = (bx + xg) / 7.0f, cy = (by + yg) / 7.0f;
    float hw = bw * 0.5f, hh = bh * 0.5f;
    float x0 = fminf(fmaxf((cx - hw) * 448.0f, 0.f), 448.f);
    float y0 = fminf(fmaxf((cy - hh) * 448.0f, 0.f), 448.f);
    float x1 = fminf(fmaxf((cx + hw) * 448.0f, 0.f), 448.f);
    float y1 = fminf(fmaxf((cy + hh) * 448.0f, 0.f), 448.f);

    size_t ci = (size_t)n * MCELLS + m;
    float* yb = out1 + ci * 5;
    nts(yb + 0, bx); nts(yb + 1, by); nts(yb + 2, bw); nts(yb + 3, bh); nts(yb + 4, conf);
    // out2/out3/out4 are re-read by K2 -> REGULAR stores (keep L2/L3-resident)
    f32x4 bx4 = { x0, y0, x1, y1 };
    *(f32x4*)(out2 + ci * 4) = bx4;
    out3[ci] = conf;
    out4[ci] = (float)labi;
    nts(out6 + ci, (conf > 0.1f) ? 1.0f : 0.0f);
  }
}

// ================= K2: NMS-only kernel =================
// Reads boxes/conf/label back (L2/L3-hot, coalesced), ballot NMS, writes keep.
__global__ __launch_bounds__(256) void yolo_nms(float* __restrict__ out, int N) {
  const int wave = threadIdx.x >> 6;
  const int lane = threadIdx.x & 63;
  const int n = blockIdx.x * 4 + wave;
  if (n >= N) return;   // wave-uniform exit

  const size_t NM = (size_t)N * MCELLS;
  const float* out2 = out + NM * 25;   // boxes
  const float* out3 = out + NM * 29;   // scores
  const float* out4 = out + NM * 30;   // labels
  float* out5 = out + NM * 31;         // keep_mask

  const int m = lane;
  const bool cellv = (m < MCELLS);
  const size_t ci = (size_t)n * MCELLS + m;

  float x0 = 0.f, y0 = 0.f, x1 = 0.f, y1 = 0.f, conf = 0.f;
  int labi = 0;
  if (cellv) {
    f32x4 b = *(const f32x4*)(out2 + ci * 4);
    x0 = b.x; y0 = b.y; x1 = b.z; y1 = b.w;
    conf = out3[ci];
    labi = (int)out4[ci];
  }
  const bool reserve = (conf > 0.1f);

  // Cross-label IoU is exactly 0 under the reference's class-offset scheme, so
  // the greedy scan == per-class greedy; keep(i) is the unique fixed point of
  // keep(i) <=> no kept candidate-suppressor (same label, higher priority, IoU>0.7).
  const bool meValid = (cellv && reserve);
  const u64 validb = __ballot(meValid);

  // same-label mask via 5 bit-ballots over the label bits (labi < 32)
  u64 same = ~0ull;
#pragma unroll
  for (int b = 0; b < 5; ++b) {
    u64 bb = __ballot(((labi >> b) & 1) != 0);
    same &= ((labi >> b) & 1) ? bb : ~bb;
  }
  u64 peers = same & validb & ~(1ull << lane);
  if (!meValid) peers = 0;

  // wave-uniform trip count = max peer count over the wave
  int pc = __popcll(peers);
#pragma unroll
  for (int d = 1; d < 64; d <<= 1) {
    int o = __shfl_xor(pc, d);
    pc = pc > o ? pc : o;
  }
  const int T = __builtin_amdgcn_readfirstlane(pc);

  // candidate-suppressor mask in ORIGINAL index space; iterations pipeline
  const float area_i = fmaxf(x1 - x0, 0.f) * fmaxf(y1 - y0, 0.f);
  u64 candme = 0;
  u64 rem = peers;
  for (int t = 0; t < T; ++t) {
    int j = rem ? (int)__builtin_ctzll(rem) : lane;   // dummy self-compare when exhausted
    rem &= rem - 1;
    float cj  = bperm(j, conf);
    float jx0 = bperm(j, x0), jy0 = bperm(j, y0);
    float jx1 = bperm(j, x1), jy1 = bperm(j, y1);
    bool prec = (cj > conf) || ((cj == conf) && (j < lane));  // stable-sort priority
    float aj = fmaxf(jx1 - jx0, 0.f) * fmaxf(jy1 - jy0, 0.f);
    float iw = fminf(jx1, x1) - fmaxf(jx0, x0);
    float ih = fminf(jy1, y1) - fmaxf(jy0, y0);
    float inter = fmaxf(iw, 0.f) * fmaxf(ih, 0.f);
    float uni = aj + area_i - inter;
    bool sup = prec && (inter > 0.7f * fmaxf(uni, 1e-9f));
    candme |= sup ? (1ull << j) : 0ull;
  }

  // ballot fixed-point: per class, the highest-priority undecided box is always
  // ready -> guaranteed progress; rounds <= max suppression-chain depth (~2-3).
  u64 undecided = validb, kept = 0;
  while (undecided) {
    bool meUnd  = meValid && ((undecided >> lane) & 1ull);
    bool ready  = meUnd && ((candme & undecided) == 0ull);
    u64 readyb  = __ballot(ready);
    u64 keptb   = __ballot(ready && ((candme & kept) == 0ull));
    kept |= keptb;
    undecided &= ~readyb;
  }

  if (cellv) nts(out5 + ci, (float)((kept >> lane) & 1ull));
}

extern "C" void kernel_launch(void* const* d_in, const int* in_sizes, int n_in,
                              void* d_out, int out_size, void* d_ws, size_t ws_size,
                              hipStream_t stream) {
  const float* x = (const float*)d_in[0];
  float* out = (float*)d_out;
  int N = in_sizes[0] / ITEMF;
  int grid = (N + 3) / 4;   // 4 waves/block, 1 item/wave
  yolo_stream<<<grid, 256, 0, stream>>>(x, out, N);
  yolo_nms<<<grid, 256, 0, stream>>>(out, N);
}

// Round 13
// 40.427 us; speedup vs baseline: 1.2471x; 1.2097x over previous
//
#include <hip/hip_runtime.h>
#include <math.h>

#define NCLS   20
#define MCELLS 49
#define FEAT   30
#define ITEMF  1470   // MCELLS * FEAT

typedef unsigned long long u64;
typedef unsigned int u32;
typedef float f32x4 __attribute__((ext_vector_type(4)));

__device__ __forceinline__ void nts(float* p, float v) { __builtin_nontemporal_store(v, p); }
__device__ __forceinline__ float bperm(int srcLane, float v) {
  return __int_as_float(__builtin_amdgcn_ds_bpermute(srcLane << 2, __float_as_int(v)));
}

__global__ __launch_bounds__(256) void yolo_post(const float* __restrict__ x,
                                                 float* __restrict__ out,
                                                 int N) {
  const int wave = threadIdx.x >> 6;
  const int lane = threadIdx.x & 63;
  const int n = blockIdx.x * 4 + wave;
  if (n >= N) return;   // wave-uniform exit; no LDS, no barriers

  const float* item = x + (size_t)n * ITEMF;

  // ---- output section pointers (flat concat in return order) ----
  const size_t NM = (size_t)N * MCELLS;
  float* out0 = out;              // class_logits  N*M*20
  float* out1 = out0 + NM * 20;   // yolo_bboxes   N*M*5
  float* out2 = out1 + NM * 5;    // boxes         N*M*4
  float* out3 = out2 + NM * 4;    // scores        N*M
  float* out4 = out3 + NM;        // labels        N*M
  float* out5 = out4 + NM;        // keep_mask     N*M
  float* out6 = out5 + NM;        // reserve_mask  N*M

  const int m = lane;
  const bool cellv = (m < MCELLS);

  // ---- per-lane AoS loads: lane m owns cell m's 30 floats (15x float2, 8B-aligned) ----
  float2 v[15];
  if (cellv) {
    const float2* Lp = (const float2*)(item + m * FEAT);
#pragma unroll
    for (int j = 0; j < 15; ++j) v[j] = Lp[j];
  } else {
#pragma unroll
    for (int j = 0; j < 15; ++j) v[j] = make_float2(0.f, 0.f);
  }

  // ---- class logits copy: global->global gather (reads are L1/L2 hits), NT stores ----
  {
    float* dst = out0 + (size_t)n * (MCELLS * NCLS);
#pragma unroll
    for (int i = 0; i < 16; ++i) {
      int idx = lane + i * 64;
      if (idx < MCELLS * NCLS) {
        int c = idx / NCLS;
        int k = idx - c * NCLS;
        nts(dst + idx, item[c * FEAT + k]);
      }
    }
  }

  // ---- per-cell compute ----
  int   labi = 0;
  float conf = 0.f;
  float x0 = 0.f, y0 = 0.f, x1 = 0.f, y1 = 0.f;
  bool  reserve = false;

  if (cellv) {
    // label = argmax over 20 logits (first-max), == argmax(softmax)
    float bestv = v[0].x;
    if (v[0].y > bestv) { bestv = v[0].y; labi = 1; }
#pragma unroll
    for (int j = 1; j < 10; ++j) {
      if (v[j].x > bestv) { bestv = v[j].x; labi = 2 * j; }
      if (v[j].y > bestv) { bestv = v[j].y; labi = 2 * j + 1; }
    }

    // bbox block elems 20..29: v[10].x=bx0 .y=by0 v[11].x=bw0 .y=bh0 v[12].x=c0
    //                          v[12].y=bx1 v[13].x=by1 .y=bw1 v[14].x=bh1 .y=c1
    float c0 = v[12].x, c1 = v[14].y;
    bool sel1 = (c1 > c0);             // argmax first-max tie rule
    float bx = sel1 ? v[12].y : v[10].x;
    float by = sel1 ? v[13].x : v[10].y;
    float bw = sel1 ? v[13].y : v[11].x;
    float bh = sel1 ? v[14].x : v[11].y;
    conf = sel1 ? c1 : c0;

    float xg = (float)(m % 7), yg = (float)(m / 7);
    float cx = (bx + xg) / 7.0f, cy = (by + yg) / 7.0f;
    float hw = bw * 0.5f, hh = bh * 0.5f;
    x0 = fminf(fmaxf((cx - hw) * 448.0f, 0.f), 448.f);
    y0 = fminf(fmaxf((cy - hh) * 448.0f, 0.f), 448.f);
    x1 = fminf(fmaxf((cx + hw) * 448.0f, 0.f), 448.f);
    y1 = fminf(fmaxf((cy + hh) * 448.0f, 0.f), 448.f);
    reserve = (conf > 0.1f);

    size_t ci = (size_t)n * MCELLS + m;
    float* yb = out1 + ci * 5;
    nts(yb + 0, bx); nts(yb + 1, by); nts(yb + 2, bw); nts(yb + 3, bh); nts(yb + 4, conf);
    f32x4 bx4 = { x0, y0, x1, y1 };
    __builtin_nontemporal_store(bx4, (f32x4*)(out2 + ci * 4));
    nts(out3 + ci, conf);
    nts(out4 + ci, (float)labi);
    nts(out6 + ci, reserve ? 1.0f : 0.0f);
  }

  // ================= NMS: sort-free, scan-free =================
  // Cross-label IoU is exactly 0 under the reference's class-offset scheme, so
  // the greedy scan == per-class greedy; keep(i) is the unique fixed point of
  // keep(i) <=> no kept candidate-suppressor (same label, higher priority, IoU>0.7).
  const bool meValid = (cellv && reserve);
  const u64 validb = __ballot(meValid);

  // same-label mask via 5 bit-ballots over the label bits (labi < 32)
  u64 same = ~0ull;
#pragma unroll
  for (int b = 0; b < 5; ++b) {
    u64 bb = __ballot(((labi >> b) & 1) != 0);
    same &= ((labi >> b) & 1) ? bb : ~bb;
  }
  u64 peers = same & validb & ~(1ull << lane);
  if (!meValid) peers = 0;

  // wave-uniform trip count = max peer count over the wave
  int pc = __popcll(peers);
#pragma unroll
  for (int d = 1; d < 64; d <<= 1) {
    int o = __shfl_xor(pc, d);
    pc = pc > o ? pc : o;
  }
  const int T = __builtin_amdgcn_readfirstlane(pc);

  // candidate-suppressor mask in ORIGINAL index space; iterations pipeline
  const float area_i = fmaxf(x1 - x0, 0.f) * fmaxf(y1 - y0, 0.f);
  u64 candme = 0;
  u64 rem = peers;
  for (int t = 0; t < T; ++t) {
    int j = rem ? (int)__builtin_ctzll(rem) : lane;   // dummy self-compare when exhausted
    rem &= rem - 1;
    float cj  = bperm(j, conf);
    float jx0 = bperm(j, x0), jy0 = bperm(j, y0);
    float jx1 = bperm(j, x1), jy1 = bperm(j, y1);
    bool prec = (cj > conf) || ((cj == conf) && (j < lane));  // stable-sort priority
    float aj = fmaxf(jx1 - jx0, 0.f) * fmaxf(jy1 - jy0, 0.f);
    float iw = fminf(jx1, x1) - fmaxf(jx0, x0);
    float ih = fminf(jy1, y1) - fmaxf(jy0, y0);
    float inter = fmaxf(iw, 0.f) * fmaxf(ih, 0.f);
    float uni = aj + area_i - inter;
    bool sup = prec && (inter > 0.7f * fmaxf(uni, 1e-9f));
    candme |= sup ? (1ull << j) : 0ull;
  }

  // ballot fixed-point: per class, the highest-priority undecided box is always
  // ready -> guaranteed progress; rounds <= max suppression-chain depth (~2-3).
  u64 undecided = validb, kept = 0;
  while (undecided) {
    bool meUnd  = meValid && ((undecided >> lane) & 1ull);
    bool ready  = meUnd && ((candme & undecided) == 0ull);
    u64 readyb  = __ballot(ready);
    u64 keptb   = __ballot(ready && ((candme & kept) == 0ull));
    kept |= keptb;
    undecided &= ~readyb;
  }

  if (cellv) nts(out5 + (size_t)n * MCELLS + m, (float)((kept >> lane) & 1ull));
}

extern "C" void kernel_launch(void* const* d_in, const int* in_sizes, int n_in,
                              void* d_out, int out_size, void* d_ws, size_t ws_size,
                              hipStream_t stream) {
  const float* x = (const float*)d_in[0];
  float* out = (float*)d_out;
  int N = in_sizes[0] / ITEMF;
  int grid = (N + 3) / 4;   // 4 waves/block, 1 item/wave
  yolo_post<<<grid, 256, 0, stream>>>(x, out, N);
}